// Round 3
// baseline (212.039 us; speedup 1.0000x reference)
//
#include <hip/hip_runtime.h>
#include <math.h>

// DCCA loss: H1,H2 (m=2048, n=64, k=128) fp32.
// Gram stage: direct global->register bf16 hi/lo split, MFMA 32x32x16, no LDS staging,
//             no main-loop barriers. One tile (64x128, both views) per wave.
// Reduce stage: per-block partials in d_ws + tree-reduce kernel (no global atomics),
//             atomic fallback if ws too small.
// Solve stage: Cholesky + triangular solves (known-correct since round 1).

// c = (1 - 1/m)^2 / (m*(m-1)) = 2047 / 2048^3
#define CSCALE 2.3830240e-7f
#define RIDGE 1e-4f

typedef __bf16 bf16x8 __attribute__((ext_vector_type(8)));
typedef float f32x16 __attribute__((ext_vector_type(16)));

#define MFMA32(A, B, C) __builtin_amdgcn_mfma_f32_32x32x16_bf16(A, B, C, 0, 0, 0)

// quadrant q -> (matrix, row-block, col-block)
__device__ __constant__ int kMat[10] = {0,0,0, 1,1,1, 2,2,2,2};
__device__ __constant__ int kQi [10] = {0,1,1, 0,1,1, 0,0,1,1};
__device__ __constant__ int kQj [10] = {0,0,1, 0,0,1, 0,1,0,1};

#define CVT8(a, b, hi, lo) do {                                   \
    float fv[8] = {a.x, a.y, a.z, a.w, b.x, b.y, b.z, b.w};       \
    _Pragma("unroll")                                             \
    for (int j = 0; j < 8; ++j) {                                 \
        __bf16 h = (__bf16)fv[j];                                 \
        hi[j] = h;                                                \
        lo[j] = (__bf16)(fv[j] - (float)h);                       \
    }                                                             \
} while (0)

template <bool PARTIALS>
__global__ __launch_bounds__(512, 2) void gram_kernel(const float* __restrict__ H1,
                                                      const float* __restrict__ H2,
                                                      float* __restrict__ sig,
                                                      float* __restrict__ part) {
    __shared__ float red[10240];
    const int tid = threadIdx.x;
    const int w = tid >> 6;
    const int lane = tid & 63;
    const int l31 = lane & 31;
    const int lhi = lane >> 5;

    // This wave's tile: rows l31 (block 0) and 32+l31 (block 1), k-cols lhi*8 + kt*16.
    const int tile = blockIdx.x * 8 + w;
    const size_t base = (size_t)tile * (64 * 128) + (size_t)l31 * 128 + lhi * 8;
    const float* __restrict__ p1 = H1 + base;
    const float* __restrict__ p2 = H2 + base;

    // 0..2: S11 (0,0),(1,0),(1,1)  3..5: S22 same  6..9: S12 (0,0),(0,1),(1,0),(1,1)
    f32x16 acc[10] = {};

    #pragma unroll
    for (int kt = 0; kt < 8; ++kt) {
        const int off = kt * 16;
        float4 r10a = *(const float4*)(p1 + off);
        float4 r10b = *(const float4*)(p1 + off + 4);
        float4 r11a = *(const float4*)(p1 + 32 * 128 + off);
        float4 r11b = *(const float4*)(p1 + 32 * 128 + off + 4);
        float4 r20a = *(const float4*)(p2 + off);
        float4 r20b = *(const float4*)(p2 + off + 4);
        float4 r21a = *(const float4*)(p2 + 32 * 128 + off);
        float4 r21b = *(const float4*)(p2 + 32 * 128 + off + 4);

        bf16x8 f1h[2], f1l[2], f2h[2], f2l[2];
        CVT8(r10a, r10b, f1h[0], f1l[0]);
        CVT8(r11a, r11b, f1h[1], f1l[1]);
        CVT8(r20a, r20b, f2h[0], f2l[0]);
        CVT8(r21a, r21b, f2h[1], f2l[1]);

        acc[0] = MFMA32(f1h[0], f1h[0], acc[0]);
        acc[0] = MFMA32(f1h[0], f1l[0], acc[0]);
        acc[0] = MFMA32(f1l[0], f1h[0], acc[0]);
        acc[1] = MFMA32(f1h[1], f1h[0], acc[1]);
        acc[1] = MFMA32(f1h[1], f1l[0], acc[1]);
        acc[1] = MFMA32(f1l[1], f1h[0], acc[1]);
        acc[2] = MFMA32(f1h[1], f1h[1], acc[2]);
        acc[2] = MFMA32(f1h[1], f1l[1], acc[2]);
        acc[2] = MFMA32(f1l[1], f1h[1], acc[2]);

        acc[3] = MFMA32(f2h[0], f2h[0], acc[3]);
        acc[3] = MFMA32(f2h[0], f2l[0], acc[3]);
        acc[3] = MFMA32(f2l[0], f2h[0], acc[3]);
        acc[4] = MFMA32(f2h[1], f2h[0], acc[4]);
        acc[4] = MFMA32(f2h[1], f2l[0], acc[4]);
        acc[4] = MFMA32(f2l[1], f2h[0], acc[4]);
        acc[5] = MFMA32(f2h[1], f2h[1], acc[5]);
        acc[5] = MFMA32(f2h[1], f2l[1], acc[5]);
        acc[5] = MFMA32(f2l[1], f2h[1], acc[5]);

        acc[6] = MFMA32(f1h[0], f2h[0], acc[6]);
        acc[6] = MFMA32(f1h[0], f2l[0], acc[6]);
        acc[6] = MFMA32(f1l[0], f2h[0], acc[6]);
        acc[7] = MFMA32(f1h[0], f2h[1], acc[7]);
        acc[7] = MFMA32(f1h[0], f2l[1], acc[7]);
        acc[7] = MFMA32(f1l[0], f2h[1], acc[7]);
        acc[8] = MFMA32(f1h[1], f2h[0], acc[8]);
        acc[8] = MFMA32(f1h[1], f2l[0], acc[8]);
        acc[8] = MFMA32(f1l[1], f2h[0], acc[8]);
        acc[9] = MFMA32(f1h[1], f2h[1], acc[9]);
        acc[9] = MFMA32(f1h[1], f2l[1], acc[9]);
        acc[9] = MFMA32(f1l[1], f2h[1], acc[9]);
    }

    // Block-level reduction in LDS (8 waves -> one copy).
    for (int i = tid; i < 10240; i += 512) red[i] = 0.0f;
    __syncthreads();
    #pragma unroll
    for (int q = 0; q < 10; ++q) {
        #pragma unroll
        for (int rg = 0; rg < 16; ++rg) {
            // C/D layout (32x32): col = lane&31, row = (rg&3) + 8*(rg>>2) + 4*(lane>>5)
            int row = (rg & 3) + 8 * (rg >> 2) + 4 * lhi;
            atomicAdd(&red[q * 1024 + row * 32 + l31], acc[q][rg]);
        }
    }
    __syncthreads();

    if (PARTIALS) {
        // Non-atomic partial dump: 10240 floats per block.
        float* dst = part + (size_t)blockIdx.x * 10240;
        for (int i = tid; i < 2560; i += 512)
            ((float4*)dst)[i] = ((const float4*)red)[i];
    } else {
        #pragma unroll
        for (int q = 0; q < 10; ++q) {
            for (int jx = tid; jx < 1024; jx += 512) {
                int r = jx >> 5, c = jx & 31;
                atomicAdd(&sig[kMat[q] * 4096 + (kQi[q] * 32 + r) * 64 + kQj[q] * 32 + c],
                          red[q * 1024 + jx]);
            }
        }
    }
}

// 160 blocks x 256 threads. Each block owns 64 consecutive partial-space outputs;
// wave w sums partial blocks {w, w+4, ...}; cross-wave combine in LDS; scatter to sig.
__global__ __launch_bounds__(256) void reduce_kernel(const float* __restrict__ part,
                                                     float* __restrict__ sig) {
    __shared__ float buf[4][64];
    const int tid = threadIdx.x;
    const int w = tid >> 6;
    const int lane = tid & 63;
    const int o0 = blockIdx.x * 64;

    float s = 0.0f;
    for (int p = w; p < 256; p += 4)
        s += part[(size_t)p * 10240 + o0 + lane];
    buf[w][lane] = s;
    __syncthreads();

    if (w == 0) {
        float v = buf[0][lane] + buf[1][lane] + buf[2][lane] + buf[3][lane];
        int o = o0 + lane;
        int q = o >> 10, idx = o & 1023;
        int r = idx >> 5, c = idx & 31;
        sig[kMat[q] * 4096 + (kQi[q] * 32 + r) * 64 + kQj[q] * 32 + c] = v;
    }
}

// One block. Scale+ridge, two Choleskys (one wave each), two unrolled triangular
// solves, Frobenius norm, -sqrt. (Known-correct; only lower triangles of S11/S22 used.)
__global__ __launch_bounds__(256) void solve_kernel(const float* __restrict__ sig,
                                                    float* __restrict__ out) {
    __shared__ float A1[64 * 68];
    __shared__ float A2[64 * 68];
    __shared__ float S [64 * 68];
    __shared__ float AS[64 * 68];
    __shared__ float Ldi[2][64];
    const int tid = threadIdx.x;

    for (int idx = tid; idx < 4096; idx += 256) {
        int r = idx >> 6, q = idx & 63;
        float rg = (r == q) ? RIDGE : 0.0f;
        A1[r * 68 + q] = CSCALE * sig[idx] + rg;
        A2[r * 68 + q] = CSCALE * sig[4096 + idx] + rg;
        S [r * 68 + q] = CSCALE * sig[8192 + idx];
    }
    __syncthreads();

    if (tid < 128) {
        float* A = (tid >= 64) ? A2 : A1;
        const int half = tid >> 6;
        const int lane = tid & 63;
        float Lrow[64];
        #pragma unroll
        for (int j = 0; j < 64; ++j) {
            float s = A[lane * 68 + j];
            #pragma unroll
            for (int tt = 0; tt < j; ++tt)
                s -= Lrow[tt] * A[j * 68 + tt];
            float dj = __shfl(s, j, 64);
            float Ljj = sqrtf(dj);
            float v = s / Ljj;
            Lrow[j] = v;
            if (lane >= j) A[lane * 68 + j] = v;
            if (lane == j) Ldi[half][j] = 1.0f / Ljj;
        }
    }
    __syncthreads();

    if (tid < 64) {
        const int c = tid;
        float y[64];
        #pragma unroll
        for (int r = 0; r < 64; ++r) {
            float s = S[r * 68 + c];
            #pragma unroll
            for (int tt = 0; tt < r; ++tt) s -= A1[r * 68 + tt] * y[tt];
            y[r] = s * Ldi[0][r];
            AS[r * 68 + c] = y[r];
        }
    }
    __syncthreads();

    if (tid < 64) {
        const int c = tid;
        float z[64];
        float nrm = 0.0f;
        #pragma unroll
        for (int r = 0; r < 64; ++r) {
            float s = AS[c * 68 + r];
            #pragma unroll
            for (int tt = 0; tt < r; ++tt) s -= A2[r * 68 + tt] * z[tt];
            z[r] = s * Ldi[1][r];
            nrm += z[r] * z[r];
        }
        #pragma unroll
        for (int off = 32; off; off >>= 1) nrm += __shfl_xor(nrm, off, 64);
        if (tid == 0) out[0] = -sqrtf(nrm);
    }
}

extern "C" void kernel_launch(void* const* d_in, const int* in_sizes, int n_in,
                              void* d_out, int out_size, void* d_ws, size_t ws_size,
                              hipStream_t stream) {
    const float* H1 = (const float*)d_in[0];
    const float* H2 = (const float*)d_in[1];
    float* sig = (float*)d_ws;                          // 12288 floats = 48 KB
    float* part = (float*)((char*)d_ws + 49152);        // 256 * 10240 floats = 10 MB
    const size_t need = 49152 + (size_t)256 * 10240 * 4;

    hipMemsetAsync(d_ws, 0, 49152, stream);
    if (ws_size >= need) {
        gram_kernel<true><<<256, 512, 0, stream>>>(H1, H2, sig, part);
        reduce_kernel<<<160, 256, 0, stream>>>(part, sig);
    } else {
        gram_kernel<false><<<256, 512, 0, stream>>>(H1, H2, sig, nullptr);
    }
    solve_kernel<<<1, 256, 0, stream>>>(sig, (float*)d_out);
}

// Round 4
// 125.156 us; speedup vs baseline: 1.6942x; 1.6942x over previous
//
#include <hip/hip_runtime.h>
#include <math.h>

// DCCA loss: H1,H2 (m=2048, n=64, k=128) fp32.
// gram: block stages tile in LDS (bf16 hi/lo), 4 waves split the 10 output quadrants
//       (<=48 acc regs/wave -> no spill). Partials to ws, tree-reduce, then Cholesky solve.
#define TPB 4
#define GRID1 512              // 2048 tiles / TPB
#define RSU 136                // LDS row stride in bf16 (272B; measured 0 conflicts in r2)
#define PLANE (64 * RSU)

// c = (1 - 1/m)^2 / (m*(m-1)) = 2047 / 2048^3
#define CSCALE 2.3830240e-7f
#define RIDGE 1e-4f

typedef __bf16 bf16x8 __attribute__((ext_vector_type(8)));
typedef float f32x16 __attribute__((ext_vector_type(16)));

#define MFMA32(A, B, C) __builtin_amdgcn_mfma_f32_32x32x16_bf16(A, B, C, 0, 0, 0)

// global quad id q -> (matrix, row-block, col-block); q0..2 S11, 3..5 S22, 6..9 S12
__device__ __constant__ int kMat[10] = {0,0,0, 1,1,1, 2,2,2,2};
__device__ __constant__ int kQi [10] = {0,1,1, 0,1,1, 0,0,1,1};
__device__ __constant__ int kQj [10] = {0,0,1, 0,0,1, 0,1,0,1};

template <bool PARTIALS>
__global__ __launch_bounds__(256, 2) void gram_kernel(const float* __restrict__ H1,
                                                      const float* __restrict__ H2,
                                                      float* __restrict__ sig,
                                                      float* __restrict__ part) {
    __shared__ __bf16 lds[4 * PLANE];   // planes: 0=H1hi 1=H1lo 2=H2hi 3=H2lo (69632 B)
    const int tid = threadIdx.x;
    const int w = tid >> 6;
    const int lane = tid & 63;
    const int l31 = lane & 31;
    const int lhi = lane >> 5;

    // wave job: w0 -> S11 quads (0,0),(1,0),(1,1); w1 -> S22 same;
    //           w2 -> S12 (0,0),(0,1); w3 -> S12 (1,0),(1,1)
    f32x16 a0 = {}, a1 = {}, a2 = {};

    for (int t = 0; t < TPB; ++t) {
        const size_t base = (size_t)(blockIdx.x * TPB + t) * (64 * 128);
        __syncthreads();  // protect LDS vs previous tile's readers
        #pragma unroll
        for (int v = 0; v < 2; ++v) {
            const float* __restrict__ Hsrc = (v ? H2 : H1) + base;
            __bf16* ph = lds + 2 * v * PLANE;
            __bf16* pl = ph + PLANE;
            #pragma unroll
            for (int it = 0; it < 4; ++it) {
                int chunk = it * 256 + tid;          // 1024 chunks of 8 floats
                int r = chunk >> 4, c8 = chunk & 15;
                const float* src = Hsrc + r * 128 + c8 * 8;
                float4 u0 = *(const float4*)src;
                float4 u1 = *(const float4*)(src + 4);
                float fv[8] = {u0.x, u0.y, u0.z, u0.w, u1.x, u1.y, u1.z, u1.w};
                bf16x8 hi, lo;
                #pragma unroll
                for (int j = 0; j < 8; ++j) {
                    __bf16 h = (__bf16)fv[j];
                    hi[j] = h;
                    lo[j] = (__bf16)(fv[j] - (float)h);
                }
                *(bf16x8*)&ph[r * RSU + c8 * 8] = hi;
                *(bf16x8*)&pl[r * RSU + c8 * 8] = lo;
            }
        }
        __syncthreads();

        if (w < 2) {
            // self-Gram of view w: A rows = output rows, B rows = output cols
            const __bf16* ph = lds + 2 * w * PLANE;
            const __bf16* pl = ph + PLANE;
            #pragma unroll
            for (int kt = 0; kt < 8; ++kt) {
                const int col = kt * 16 + lhi * 8;
                bf16x8 h0 = *(const bf16x8*)&ph[l31 * RSU + col];
                bf16x8 h1 = *(const bf16x8*)&ph[(32 + l31) * RSU + col];
                bf16x8 l0 = *(const bf16x8*)&pl[l31 * RSU + col];
                bf16x8 l1 = *(const bf16x8*)&pl[(32 + l31) * RSU + col];
                a0 = MFMA32(h0, h0, a0); a0 = MFMA32(h0, l0, a0); a0 = MFMA32(l0, h0, a0);
                a1 = MFMA32(h1, h0, a1); a1 = MFMA32(h1, l0, a1); a1 = MFMA32(l1, h0, a1);
                a2 = MFMA32(h1, h1, a2); a2 = MFMA32(h1, l1, a2); a2 = MFMA32(l1, h1, a2);
            }
        } else {
            // S12 row-block (w-2): A = H1 block qi, B = H2 blocks 0/1
            const int arow = ((w == 3) ? 32 : 0) + l31;
            #pragma unroll
            for (int kt = 0; kt < 8; ++kt) {
                const int col = kt * 16 + lhi * 8;
                bf16x8 Ah  = *(const bf16x8*)&lds[0 * PLANE + arow * RSU + col];
                bf16x8 Al  = *(const bf16x8*)&lds[1 * PLANE + arow * RSU + col];
                bf16x8 B0h = *(const bf16x8*)&lds[2 * PLANE + l31 * RSU + col];
                bf16x8 B0l = *(const bf16x8*)&lds[3 * PLANE + l31 * RSU + col];
                bf16x8 B1h = *(const bf16x8*)&lds[2 * PLANE + (32 + l31) * RSU + col];
                bf16x8 B1l = *(const bf16x8*)&lds[3 * PLANE + (32 + l31) * RSU + col];
                a0 = MFMA32(Ah, B0h, a0); a0 = MFMA32(Ah, B0l, a0); a0 = MFMA32(Al, B0h, a0);
                a1 = MFMA32(Ah, B1h, a1); a1 = MFMA32(Ah, B1l, a1); a1 = MFMA32(Al, B1h, a1);
            }
        }
    }

    // Flush: quads are wave-disjoint -> non-atomic partial dump (or atomic fallback).
    const int q0 = (w == 0) ? 0 : (w == 1) ? 3 : (w == 2) ? 6 : 8;
    const int nq = (w < 2) ? 3 : 2;
    f32x16 A[3] = {a0, a1, a2};
    if (PARTIALS) {
        float* dst = part + (size_t)blockIdx.x * 10240 + q0 * 1024;
        #pragma unroll
        for (int qq = 0; qq < 3; ++qq) {
            if (qq < nq) {
                #pragma unroll
                for (int rg = 0; rg < 16; ++rg) {
                    // C/D 32x32 layout: col = lane&31, row = (rg&3)+8*(rg>>2)+4*(lane>>5)
                    int row = (rg & 3) + 8 * (rg >> 2) + 4 * lhi;
                    dst[qq * 1024 + row * 32 + l31] = A[qq][rg];
                }
            }
        }
    } else {
        #pragma unroll
        for (int qq = 0; qq < 3; ++qq) {
            if (qq < nq) {
                const int q = q0 + qq;
                #pragma unroll
                for (int rg = 0; rg < 16; ++rg) {
                    int row = (rg & 3) + 8 * (rg >> 2) + 4 * lhi;
                    atomicAdd(&sig[kMat[q] * 4096 + (kQi[q] * 32 + row) * 64 + kQj[q] * 32 + l31],
                              A[qq][rg]);
                }
            }
        }
    }
}

// 160 blocks x 256 threads: block owns 64 partial-space slots; wave w sums slabs
// {w, w+4, ...}; cross-wave combine in LDS; scatter into sig.
__global__ __launch_bounds__(256) void reduce_kernel(const float* __restrict__ part,
                                                     float* __restrict__ sig) {
    __shared__ float buf[4][64];
    const int tid = threadIdx.x;
    const int w = tid >> 6;
    const int lane = tid & 63;
    const int o0 = blockIdx.x * 64;

    float s = 0.0f;
    for (int p = w; p < GRID1; p += 4)
        s += part[(size_t)p * 10240 + o0 + lane];
    buf[w][lane] = s;
    __syncthreads();

    if (w == 0) {
        float v = buf[0][lane] + buf[1][lane] + buf[2][lane] + buf[3][lane];
        int o = o0 + lane;
        int q = o >> 10, idx = o & 1023;
        int r = idx >> 5, c = idx & 31;
        sig[kMat[q] * 4096 + (kQi[q] * 32 + r) * 64 + kQj[q] * 32 + c] = v;
    }
}

// One block. Scale+ridge, two Choleskys (one wave each), two unrolled triangular
// solves, Frobenius norm, -sqrt. (Known-correct; only lower triangles of S11/S22 used.)
__global__ __launch_bounds__(256) void solve_kernel(const float* __restrict__ sig,
                                                    float* __restrict__ out) {
    __shared__ float A1[64 * 68];
    __shared__ float A2[64 * 68];
    __shared__ float S [64 * 68];
    __shared__ float AS[64 * 68];
    __shared__ float Ldi[2][64];
    const int tid = threadIdx.x;

    for (int idx = tid; idx < 4096; idx += 256) {
        int r = idx >> 6, q = idx & 63;
        float rg = (r == q) ? RIDGE : 0.0f;
        A1[r * 68 + q] = CSCALE * sig[idx] + rg;
        A2[r * 68 + q] = CSCALE * sig[4096 + idx] + rg;
        S [r * 68 + q] = CSCALE * sig[8192 + idx];
    }
    __syncthreads();

    if (tid < 128) {
        float* A = (tid >= 64) ? A2 : A1;
        const int half = tid >> 6;
        const int lane = tid & 63;
        float Lrow[64];
        #pragma unroll
        for (int j = 0; j < 64; ++j) {
            float s = A[lane * 68 + j];
            #pragma unroll
            for (int tt = 0; tt < j; ++tt)
                s -= Lrow[tt] * A[j * 68 + tt];
            float dj = __shfl(s, j, 64);
            float Ljj = sqrtf(dj);
            float v = s / Ljj;
            Lrow[j] = v;
            if (lane >= j) A[lane * 68 + j] = v;
            if (lane == j) Ldi[half][j] = 1.0f / Ljj;
        }
    }
    __syncthreads();

    if (tid < 64) {
        const int c = tid;
        float y[64];
        #pragma unroll
        for (int r = 0; r < 64; ++r) {
            float s = S[r * 68 + c];
            #pragma unroll
            for (int tt = 0; tt < r; ++tt) s -= A1[r * 68 + tt] * y[tt];
            y[r] = s * Ldi[0][r];
            AS[r * 68 + c] = y[r];
        }
    }
    __syncthreads();

    if (tid < 64) {
        const int c = tid;
        float z[64];
        float nrm = 0.0f;
        #pragma unroll
        for (int r = 0; r < 64; ++r) {
            float s = AS[c * 68 + r];
            #pragma unroll
            for (int tt = 0; tt < r; ++tt) s -= A2[r * 68 + tt] * z[tt];
            z[r] = s * Ldi[1][r];
            nrm += z[r] * z[r];
        }
        #pragma unroll
        for (int off = 32; off; off >>= 1) nrm += __shfl_xor(nrm, off, 64);
        if (tid == 0) out[0] = -sqrtf(nrm);
    }
}

extern "C" void kernel_launch(void* const* d_in, const int* in_sizes, int n_in,
                              void* d_out, int out_size, void* d_ws, size_t ws_size,
                              hipStream_t stream) {
    const float* H1 = (const float*)d_in[0];
    const float* H2 = (const float*)d_in[1];
    float* sig = (float*)d_ws;                      // 12288 floats = 48 KB
    float* part = (float*)((char*)d_ws + 49152);    // 512 * 10240 floats = 20 MB
    const size_t need = 49152 + (size_t)GRID1 * 10240 * 4;

    hipMemsetAsync(d_ws, 0, 49152, stream);
    if (ws_size >= need) {
        gram_kernel<true><<<GRID1, 256, 0, stream>>>(H1, H2, sig, part);
        reduce_kernel<<<160, 256, 0, stream>>>(part, sig);
    } else {
        gram_kernel<false><<<GRID1, 256, 0, stream>>>(H1, H2, sig, nullptr);
    }
    solve_kernel<<<1, 256, 0, stream>>>(sig, (float*)d_out);
}

// Round 5
// 90.805 us; speedup vs baseline: 2.3351x; 1.3783x over previous
//
#include <hip/hip_runtime.h>
#include <math.h>

// DCCA loss: H1,H2 (m=2048, n=64, k=128) fp32.
// gram: block stages tile in LDS (bf16 hi/lo), 4 waves split the 10 output quadrants.
// reduce: tree-reduce partials into sig.
// solve: MFMA Newton inverse (X=A^-1), corr^2 = <X1, S12 X2 S12^T>, -sqrt.
#define TPB 4
#define GRID1 512              // 2048 tiles / TPB
#define RSU 136                // gram LDS row stride in bf16
#define PLANE (64 * RSU)

// c = (1 - 1/m)^2 / (m*(m-1)) = 2047 / 2048^3
#define CSCALE 2.3830240e-7f
#define RIDGE 1e-4f

typedef __bf16 bf16x8 __attribute__((ext_vector_type(8)));
typedef float f32x16 __attribute__((ext_vector_type(16)));

#define MFMA32(A, B, C) __builtin_amdgcn_mfma_f32_32x32x16_bf16(A, B, C, 0, 0, 0)

// global quad id q -> (matrix, row-block, col-block); q0..2 S11, 3..5 S22, 6..9 S12
__device__ __constant__ int kMat[10] = {0,0,0, 1,1,1, 2,2,2,2};
__device__ __constant__ int kQi [10] = {0,1,1, 0,1,1, 0,0,1,1};
__device__ __constant__ int kQj [10] = {0,0,1, 0,0,1, 0,1,0,1};

template <bool PARTIALS>
__global__ __launch_bounds__(256, 2) void gram_kernel(const float* __restrict__ H1,
                                                      const float* __restrict__ H2,
                                                      float* __restrict__ sig,
                                                      float* __restrict__ part) {
    __shared__ __bf16 lds[4 * PLANE];   // planes: 0=H1hi 1=H1lo 2=H2hi 3=H2lo (69632 B)
    const int tid = threadIdx.x;
    const int w = tid >> 6;
    const int lane = tid & 63;
    const int l31 = lane & 31;
    const int lhi = lane >> 5;

    // wave job: w0 -> S11 quads (0,0),(1,0),(1,1); w1 -> S22 same;
    //           w2 -> S12 (0,0),(0,1); w3 -> S12 (1,0),(1,1)
    f32x16 a0 = {}, a1 = {}, a2 = {};

    for (int t = 0; t < TPB; ++t) {
        const size_t base = (size_t)(blockIdx.x * TPB + t) * (64 * 128);
        __syncthreads();  // protect LDS vs previous tile's readers
        #pragma unroll
        for (int v = 0; v < 2; ++v) {
            const float* __restrict__ Hsrc = (v ? H2 : H1) + base;
            __bf16* ph = lds + 2 * v * PLANE;
            __bf16* pllo = ph + PLANE;
            #pragma unroll
            for (int it = 0; it < 4; ++it) {
                int chunk = it * 256 + tid;          // 1024 chunks of 8 floats
                int r = chunk >> 4, c8 = chunk & 15;
                const float* src = Hsrc + r * 128 + c8 * 8;
                float4 u0 = *(const float4*)src;
                float4 u1 = *(const float4*)(src + 4);
                float fv[8] = {u0.x, u0.y, u0.z, u0.w, u1.x, u1.y, u1.z, u1.w};
                bf16x8 hi, lo;
                #pragma unroll
                for (int j = 0; j < 8; ++j) {
                    __bf16 h = (__bf16)fv[j];
                    hi[j] = h;
                    lo[j] = (__bf16)(fv[j] - (float)h);
                }
                *(bf16x8*)&ph[r * RSU + c8 * 8] = hi;
                *(bf16x8*)&pllo[r * RSU + c8 * 8] = lo;
            }
        }
        __syncthreads();

        if (w < 2) {
            const __bf16* ph = lds + 2 * w * PLANE;
            const __bf16* pllo = ph + PLANE;
            #pragma unroll
            for (int kt = 0; kt < 8; ++kt) {
                const int col = kt * 16 + lhi * 8;
                bf16x8 h0 = *(const bf16x8*)&ph[l31 * RSU + col];
                bf16x8 h1 = *(const bf16x8*)&ph[(32 + l31) * RSU + col];
                bf16x8 l0 = *(const bf16x8*)&pllo[l31 * RSU + col];
                bf16x8 l1 = *(const bf16x8*)&pllo[(32 + l31) * RSU + col];
                a0 = MFMA32(h0, h0, a0); a0 = MFMA32(h0, l0, a0); a0 = MFMA32(l0, h0, a0);
                a1 = MFMA32(h1, h0, a1); a1 = MFMA32(h1, l0, a1); a1 = MFMA32(l1, h0, a1);
                a2 = MFMA32(h1, h1, a2); a2 = MFMA32(h1, l1, a2); a2 = MFMA32(l1, h1, a2);
            }
        } else {
            const int arow = ((w == 3) ? 32 : 0) + l31;
            #pragma unroll
            for (int kt = 0; kt < 8; ++kt) {
                const int col = kt * 16 + lhi * 8;
                bf16x8 Ahf = *(const bf16x8*)&lds[0 * PLANE + arow * RSU + col];
                bf16x8 Alf = *(const bf16x8*)&lds[1 * PLANE + arow * RSU + col];
                bf16x8 B0h = *(const bf16x8*)&lds[2 * PLANE + l31 * RSU + col];
                bf16x8 B0l = *(const bf16x8*)&lds[3 * PLANE + l31 * RSU + col];
                bf16x8 B1h = *(const bf16x8*)&lds[2 * PLANE + (32 + l31) * RSU + col];
                bf16x8 B1l = *(const bf16x8*)&lds[3 * PLANE + (32 + l31) * RSU + col];
                a0 = MFMA32(Ahf, B0h, a0); a0 = MFMA32(Ahf, B0l, a0); a0 = MFMA32(Alf, B0h, a0);
                a1 = MFMA32(Ahf, B1h, a1); a1 = MFMA32(Ahf, B1l, a1); a1 = MFMA32(Alf, B1h, a1);
            }
        }
    }

    const int q0 = (w == 0) ? 0 : (w == 1) ? 3 : (w == 2) ? 6 : 8;
    const int nq = (w < 2) ? 3 : 2;
    f32x16 A[3] = {a0, a1, a2};
    if (PARTIALS) {
        float* dst = part + (size_t)blockIdx.x * 10240 + q0 * 1024;
        #pragma unroll
        for (int qq = 0; qq < 3; ++qq) {
            if (qq < nq) {
                #pragma unroll
                for (int rg = 0; rg < 16; ++rg) {
                    int row = (rg & 3) + 8 * (rg >> 2) + 4 * lhi;
                    dst[qq * 1024 + row * 32 + l31] = A[qq][rg];
                }
            }
        }
    } else {
        #pragma unroll
        for (int qq = 0; qq < 3; ++qq) {
            if (qq < nq) {
                const int q = q0 + qq;
                #pragma unroll
                for (int rg = 0; rg < 16; ++rg) {
                    int row = (rg & 3) + 8 * (rg >> 2) + 4 * lhi;
                    atomicAdd(&sig[kMat[q] * 4096 + (kQi[q] * 32 + row) * 64 + kQj[q] * 32 + l31],
                              A[qq][rg]);
                }
            }
        }
    }
}

__global__ __launch_bounds__(256) void reduce_kernel(const float* __restrict__ part,
                                                     float* __restrict__ sig) {
    __shared__ float buf[4][64];
    const int tid = threadIdx.x;
    const int w = tid >> 6;
    const int lane = tid & 63;
    const int o0 = blockIdx.x * 64;

    float s = 0.0f;
    for (int p = w; p < GRID1; p += 4)
        s += part[(size_t)p * 10240 + o0 + lane];
    buf[w][lane] = s;
    __syncthreads();

    if (w == 0) {
        float v = buf[0][lane] + buf[1][lane] + buf[2][lane] + buf[3][lane];
        int o = o0 + lane;
        int q = o >> 10, idx = o & 1023;
        int r = idx >> 5, c = idx & 31;
        sig[kMat[q] * 4096 + (kQi[q] * 32 + r) * 64 + kQj[q] * 32 + c] = v;
    }
}

// One block, 512 threads (8 waves). Newton inverse on MFMA:
//   X0 = (64/tr A) I;  X <- 2X - X*A*X  (4 iters, quadratic convergence)
//   corr^2 = <X1, S12*X2*S12^T>  computed transpose-free via mfma(A,B)=A*B^T + symmetry.
// bf16 hi/lo planes, stride 72 (144B rows, 16B-aligned).
#define SST 72
#define SPL (64 * SST)
// plane ids: 0/1 A1 h/l, 2/3 A2 h/l, 4/5 X1 h/l, 6/7 X2 h/l, 8/9 W1|S12 h/l, 10/11 W2|Z h/l

__global__ __launch_bounds__(512, 1) void solve_kernel(const float* __restrict__ sig,
                                                       float* __restrict__ out) {
    __shared__ __attribute__((aligned(16))) __bf16 pl[12 * SPL];
    __shared__ float ainv[2];
    __shared__ float rbuf[4];
    const int tid = threadIdx.x;
    const int w = tid >> 6, lane = tid & 63, l31 = lane & 31, lhi = lane >> 5;
    const int g = w >> 2;          // matrix group: 0 -> S11, 1 -> S22
    const int qw = w & 3, qi = qw >> 1, qj = qw & 1;
    const int ra = qi * 32 + l31;  // A-operand fragment row
    const int rb = qj * 32 + l31;  // B-operand fragment row

    // Load A = CSCALE*Gram + ridge, symmetric reconstruct (sig quad (0,1) is zeros).
    for (int idx = tid; idx < 4096; idx += 512) {
        int r = idx >> 6, c = idx & 63;
        int src = (r < 32 && c >= 32) ? (c * 64 + r) : idx;
        float rg = (r == c) ? RIDGE : 0.0f;
        float a1 = CSCALE * sig[src] + rg;
        float a2 = CSCALE * sig[4096 + src] + rg;
        __bf16 h1 = (__bf16)a1, h2 = (__bf16)a2;
        pl[0 * SPL + r * SST + c] = h1;
        pl[1 * SPL + r * SST + c] = (__bf16)(a1 - (float)h1);
        pl[2 * SPL + r * SST + c] = h2;
        pl[3 * SPL + r * SST + c] = (__bf16)(a2 - (float)h2);
    }
    if (w == 0 || w == 4) {        // alpha_inv = 64 / tr(A)
        int mg = (w == 4);
        float d = CSCALE * sig[mg * 4096 + lane * 65] + RIDGE;
        #pragma unroll
        for (int off = 32; off; off >>= 1) d += __shfl_xor(d, off, 64);
        if (lane == 0) ainv[mg] = 64.0f / d;
    }
    __syncthreads();

    // X0 = ainv * I
    for (int idx = tid; idx < 4096; idx += 512) {
        int r = idx >> 6, c = idx & 63;
        float v1 = (r == c) ? ainv[0] : 0.0f;
        float v2 = (r == c) ? ainv[1] : 0.0f;
        __bf16 h1 = (__bf16)v1, h2 = (__bf16)v2;
        pl[4 * SPL + r * SST + c] = h1;
        pl[5 * SPL + r * SST + c] = (__bf16)(v1 - (float)h1);
        pl[6 * SPL + r * SST + c] = h2;
        pl[7 * SPL + r * SST + c] = (__bf16)(v2 - (float)h2);
    }
    __syncthreads();

    for (int it = 0; it < 4; ++it) {
        // W = X * A  (= mfma(X rows, A rows), both symmetric)
        f32x16 accw = {};
        #pragma unroll
        for (int ks = 0; ks < 4; ++ks) {
            int col = ks * 16 + lhi * 8;
            bf16x8 xh = *(const bf16x8*)&pl[(4 + 2 * g) * SPL + ra * SST + col];
            bf16x8 xl = *(const bf16x8*)&pl[(5 + 2 * g) * SPL + ra * SST + col];
            bf16x8 ah = *(const bf16x8*)&pl[(0 + 2 * g) * SPL + rb * SST + col];
            bf16x8 al = *(const bf16x8*)&pl[(1 + 2 * g) * SPL + rb * SST + col];
            accw = MFMA32(xh, ah, accw);
            accw = MFMA32(xh, al, accw);
            accw = MFMA32(xl, ah, accw);
        }
        #pragma unroll
        for (int rg = 0; rg < 16; ++rg) {
            int row = qi * 32 + (rg & 3) + 8 * (rg >> 2) + 4 * lhi;
            int col = qj * 32 + l31;
            float v = accw[rg];
            __bf16 h = (__bf16)v;
            pl[(8 + 2 * g) * SPL + row * SST + col] = h;
            pl[(9 + 2 * g) * SPL + row * SST + col] = (__bf16)(v - (float)h);
        }
        __syncthreads();

        // S = W * X ; X <- 2X - S
        f32x16 accs = {};
        #pragma unroll
        for (int ks = 0; ks < 4; ++ks) {
            int col = ks * 16 + lhi * 8;
            bf16x8 wh = *(const bf16x8*)&pl[(8 + 2 * g) * SPL + ra * SST + col];
            bf16x8 wl = *(const bf16x8*)&pl[(9 + 2 * g) * SPL + ra * SST + col];
            bf16x8 xh = *(const bf16x8*)&pl[(4 + 2 * g) * SPL + rb * SST + col];
            bf16x8 xl = *(const bf16x8*)&pl[(5 + 2 * g) * SPL + rb * SST + col];
            accs = MFMA32(wh, xh, accs);
            accs = MFMA32(wh, xl, accs);
            accs = MFMA32(wl, xh, accs);
        }
        __syncthreads();   // all X reads done before X writes
        #pragma unroll
        for (int rg = 0; rg < 16; ++rg) {
            int row = qi * 32 + (rg & 3) + 8 * (rg >> 2) + 4 * lhi;
            int col = qj * 32 + l31;
            float xv = (float)pl[(4 + 2 * g) * SPL + row * SST + col]
                     + (float)pl[(5 + 2 * g) * SPL + row * SST + col];
            float nv = 2.0f * xv - accs[rg];
            __bf16 h = (__bf16)nv;
            pl[(4 + 2 * g) * SPL + row * SST + col] = h;
            pl[(5 + 2 * g) * SPL + row * SST + col] = (__bf16)(nv - (float)h);
        }
        __syncthreads();
    }

    // S12 -> planes 8/9 (W1 planes, free now)
    for (int idx = tid; idx < 4096; idx += 512) {
        int r = idx >> 6, c = idx & 63;
        float v = CSCALE * sig[8192 + idx];
        __bf16 h = (__bf16)v;
        pl[8 * SPL + r * SST + c] = h;
        pl[9 * SPL + r * SST + c] = (__bf16)(v - (float)h);
    }
    __syncthreads();

    // Z = S12 * X2 -> planes 10/11 (group 1)
    if (g == 1) {
        f32x16 accz = {};
        #pragma unroll
        for (int ks = 0; ks < 4; ++ks) {
            int col = ks * 16 + lhi * 8;
            bf16x8 sh = *(const bf16x8*)&pl[8 * SPL + ra * SST + col];
            bf16x8 sl = *(const bf16x8*)&pl[9 * SPL + ra * SST + col];
            bf16x8 xh = *(const bf16x8*)&pl[6 * SPL + rb * SST + col];
            bf16x8 xl = *(const bf16x8*)&pl[7 * SPL + rb * SST + col];
            accz = MFMA32(sh, xh, accz);
            accz = MFMA32(sh, xl, accz);
            accz = MFMA32(sl, xh, accz);
        }
        #pragma unroll
        for (int rg = 0; rg < 16; ++rg) {
            int row = qi * 32 + (rg & 3) + 8 * (rg >> 2) + 4 * lhi;
            int col = qj * 32 + l31;
            float v = accz[rg];
            __bf16 h = (__bf16)v;
            pl[10 * SPL + row * SST + col] = h;
            pl[11 * SPL + row * SST + col] = (__bf16)(v - (float)h);
        }
    }
    __syncthreads();

    // M = Z * S12^T (group 0); corr^2 += M .* X1
    if (g == 0) {
        f32x16 accm = {};
        #pragma unroll
        for (int ks = 0; ks < 4; ++ks) {
            int col = ks * 16 + lhi * 8;
            bf16x8 zh = *(const bf16x8*)&pl[10 * SPL + ra * SST + col];
            bf16x8 zl = *(const bf16x8*)&pl[11 * SPL + ra * SST + col];
            bf16x8 sh = *(const bf16x8*)&pl[8 * SPL + rb * SST + col];
            bf16x8 sl = *(const bf16x8*)&pl[9 * SPL + rb * SST + col];
            accm = MFMA32(zh, sh, accm);
            accm = MFMA32(zh, sl, accm);
            accm = MFMA32(zl, sh, accm);
        }
        float p = 0.0f;
        #pragma unroll
        for (int rg = 0; rg < 16; ++rg) {
            int row = qi * 32 + (rg & 3) + 8 * (rg >> 2) + 4 * lhi;
            int col = qj * 32 + l31;
            float x1v = (float)pl[4 * SPL + row * SST + col]
                      + (float)pl[5 * SPL + row * SST + col];
            p += accm[rg] * x1v;
        }
        #pragma unroll
        for (int off = 32; off; off >>= 1) p += __shfl_xor(p, off, 64);
        if (lane == 0) rbuf[qw] = p;
    }
    __syncthreads();
    if (tid == 0) out[0] = -sqrtf(rbuf[0] + rbuf[1] + rbuf[2] + rbuf[3]);
}

extern "C" void kernel_launch(void* const* d_in, const int* in_sizes, int n_in,
                              void* d_out, int out_size, void* d_ws, size_t ws_size,
                              hipStream_t stream) {
    const float* H1 = (const float*)d_in[0];
    const float* H2 = (const float*)d_in[1];
    float* sig = (float*)d_ws;                      // 12288 floats = 48 KB
    float* part = (float*)((char*)d_ws + 49152);    // 512 * 10240 floats = 20 MB
    const size_t need = 49152 + (size_t)GRID1 * 10240 * 4;

    hipMemsetAsync(d_ws, 0, 49152, stream);
    if (ws_size >= need) {
        gram_kernel<true><<<GRID1, 256, 0, stream>>>(H1, H2, sig, part);
        reduce_kernel<<<160, 256, 0, stream>>>(part, sig);
    } else {
        gram_kernel<false><<<GRID1, 256, 0, stream>>>(H1, H2, sig, nullptr);
    }
    solve_kernel<<<1, 512, 0, stream>>>(sig, (float*)d_out);
}